// Round 1
// baseline (1227.475 us; speedup 1.0000x reference)
//
#include <hip/hip_runtime.h>
#include <math.h>

// Problem: x [64,3,224,224] fp32
//   expert: conv3x3 s2 SAME (3->64)+ReLU -> [64,64,112,112]
//           conv3x3 s2 SAME (64->128)+ReLU -> [64,128,56,56]
//           GAP -> [64,128]; FC 128->2
//   blend on t-expert softmax confidence <= 0.9
// Output: 129 floats: out[64,2] flat + freq_usage
//
// SAME padding (XLA): pad_total=1 -> pad_lo=0, pad_hi=1 for both convs.
//
// ws layout (floats):
//   [0, 147456)        w2t[2][576][128]  (k = ic*9+kh*3+kw, oc contiguous)
//   [147456, 163840)   g[2][64][128]     pooled (un-normalized relu sums)

__global__ __launch_bounds__(256) void transpose_w2(
    const float* __restrict__ w2_t, const float* __restrict__ w2_f,
    float* __restrict__ w2t) {
  int idx = blockIdx.x * 256 + threadIdx.x;   // [0, 147456)
  int e = idx / 73728;
  int r = idx - e * 73728;
  int k = r >> 7;          // [0,576)
  int oc = r & 127;        // [0,128)
  const float* src = e ? w2_f : w2_t;         // [oc][ic][3][3] = [oc][k]
  w2t[idx] = src[oc * 576 + k];
}

// Fused conv1+conv2+pool. Block: 256 threads.
// Tile: conv2 out rows [4*ty,4*ty+4), cols [28*tx,28*tx+28), all 128 oc.
// Needs h1 local tile 9 x 57 (global rows 8ty..8ty+8, cols 56tx..56tx+56),
// x local tile 19 x 115 (global rows 16ty.., cols 112tx..).
__global__ __launch_bounds__(256, 3) void fused_expert(
    const float* __restrict__ x,
    const float* __restrict__ w1_t, const float* __restrict__ b1_t,
    const float* __restrict__ b2_t,
    const float* __restrict__ w1_f, const float* __restrict__ b1_f,
    const float* __restrict__ b2_f,
    const float* __restrict__ w2t_all,   // [2][576][128]
    float* __restrict__ g)               // [2][64][128]
{
  const int tile = blockIdx.x;   // 0..27
  const int b    = blockIdx.y;   // 0..63
  const int e    = blockIdx.z;   // 0..1
  const int ty = tile >> 1;      // 0..13
  const int tx = tile & 1;       // 0..1

  const float* w1  = e ? w1_f : w1_t;
  const float* b1  = e ? b1_f : b1_t;
  const float* b2  = e ? b2_f : b2_t;
  const float* w2t = w2t_all + e * 73728;

  __shared__ float x_s[3 * 19 * 116];   // 6612 floats (rows padded to 116)
  __shared__ float h1_s[8 * 9 * 58];    // 4176 floats (8 ic-chunk, rows pad 58)
  __shared__ float w1_s[1728];          // full w1 [64][27]

  const int tid = threadIdx.x;

  // ---- stage x tile + w1 ----
  {
    const float* xb = x + (size_t)b * (3 * 224 * 224);
    const int xr0 = ty * 16, xc0 = tx * 112;
    for (int idx = tid; idx < 3 * 19 * 116; idx += 256) {
      int ic  = idx / (19 * 116);
      int rem = idx - ic * (19 * 116);
      int r   = rem / 116;
      int cc  = rem - r * 116;
      int xr = xr0 + r, xc = xc0 + cc;
      float v = 0.f;
      if (xr < 224 && xc < 224 && cc < 115)
        v = xb[(ic * 224 + xr) * 224 + xc];
      x_s[idx] = v;
    }
    for (int idx = tid; idx < 1728; idx += 256) w1_s[idx] = w1[idx];
  }

  // ---- conv2 thread mapping: 16 oc-groups x 16 pos-groups ----
  const int ocg  = tid >> 4;   // 0..15 -> oc = ocg*8 .. +7
  const int posg = tid & 15;   // 0..15 -> pos = posg + 16*j, j=0..6
  int pbase[7];
#pragma unroll
  for (int j = 0; j < 7; ++j) {
    int p  = posg + 16 * j;    // 0..111
    int py = p / 28;           // 0..3
    int px = p - py * 28;      // 0..27
    pbase[j] = py * 2 * 58 + px * 2;
  }
  float acc[7][8];
#pragma unroll
  for (int j = 0; j < 7; ++j)
#pragma unroll
    for (int i = 0; i < 8; ++i) acc[j][i] = 0.f;

  // ---- conv1 thread mapping: 8 channel-groups x 32 threads ----
  const int hc_l = tid >> 5;   // 0..7
  const int l32  = tid & 31;

  for (int c = 0; c < 8; ++c) {
    __syncthreads();  // h1_s consumers of previous chunk done
    // conv1: produce h1 chunk channels c*8 + hc_l over 9x57 tile
    {
      const int hc = c * 8 + hc_l;
      const float bias = b1[hc];
      float wr[27];
#pragma unroll
      for (int q = 0; q < 27; ++q) wr[q] = w1_s[hc * 27 + q];
      for (int p = l32; p < 513; p += 32) {   // 9*57 = 513
        int hy = p / 57;
        int hx = p - hy * 57;
        float a = bias;
#pragma unroll
        for (int ic = 0; ic < 3; ++ic)
#pragma unroll
          for (int kh = 0; kh < 3; ++kh) {
            const float* row = &x_s[ic * (19 * 116) + (2 * hy + kh) * 116 + 2 * hx];
            a = fmaf(row[0], wr[ic * 9 + kh * 3 + 0], a);
            a = fmaf(row[1], wr[ic * 9 + kh * 3 + 1], a);
            a = fmaf(row[2], wr[ic * 9 + kh * 3 + 2], a);
          }
        float v = fmaxf(a, 0.f);
        // conv2's SAME pad of h1: global row/col 112 must be zero
        int hy_g = ty * 8 + hy;
        int hx_g = tx * 56 + hx;
        if (hy_g >= 112 || hx_g >= 112) v = 0.f;
        h1_s[hc_l * 522 + hy * 58 + hx] = v;
      }
    }
    __syncthreads();
    // conv2 partial over this ic chunk
    for (int ic_l = 0; ic_l < 8; ++ic_l) {
#pragma unroll
      for (int kh = 0; kh < 3; ++kh)
#pragma unroll
        for (int kw = 0; kw < 3; ++kw) {
          const int k = (c * 8 + ic_l) * 9 + kh * 3 + kw;
          const float4 wA = *(const float4*)(w2t + k * 128 + ocg * 8);
          const float4 wB = *(const float4*)(w2t + k * 128 + ocg * 8 + 4);
          const float* hp = &h1_s[ic_l * 522 + kh * 58 + kw];
#pragma unroll
          for (int j = 0; j < 7; ++j) {
            float h = hp[pbase[j]];
            acc[j][0] = fmaf(wA.x, h, acc[j][0]);
            acc[j][1] = fmaf(wA.y, h, acc[j][1]);
            acc[j][2] = fmaf(wA.z, h, acc[j][2]);
            acc[j][3] = fmaf(wA.w, h, acc[j][3]);
            acc[j][4] = fmaf(wB.x, h, acc[j][4]);
            acc[j][5] = fmaf(wB.y, h, acc[j][5]);
            acc[j][6] = fmaf(wB.z, h, acc[j][6]);
            acc[j][7] = fmaf(wB.w, h, acc[j][7]);
          }
        }
    }
  }

  // ---- epilogue: +b2, ReLU, pool, block-reduce, atomic to g ----
  __syncthreads();
  float* red = x_s;  // reuse x_s region: 16*129 = 2064 floats
#pragma unroll
  for (int i = 0; i < 8; ++i) {
    float bb = b2[ocg * 8 + i];
    float t = 0.f;
#pragma unroll
    for (int j = 0; j < 7; ++j) t += fmaxf(acc[j][i] + bb, 0.f);
    red[posg * 129 + ocg * 8 + i] = t;
  }
  __syncthreads();
  if (tid < 128) {
    float t = 0.f;
#pragma unroll
    for (int pg = 0; pg < 16; ++pg) t += red[pg * 129 + tid];
    atomicAdd(&g[(e * 64 + b) * 128 + tid], t);
  }
}

// FC + softmax-confidence routing + blend + freq. 1 block, 1 wave.
__global__ __launch_bounds__(64) void finale(
    const float* __restrict__ g,
    const float* __restrict__ t_wf, const float* __restrict__ t_bf,
    const float* __restrict__ f_wf, const float* __restrict__ f_bf,
    float* __restrict__ out)
{
  const int b = threadIdx.x;  // 0..63
  const float inv = 1.0f / 3136.0f;
  const float* gt = g + b * 128;
  const float* gf = g + (64 + b) * 128;
  float lt0 = t_bf[0], lt1 = t_bf[1];
  float lf0 = f_bf[0], lf1 = f_bf[1];
  for (int k = 0; k < 128; ++k) {
    float vt = gt[k] * inv;
    float vf = gf[k] * inv;
    lt0 = fmaf(vt, t_wf[2 * k],     lt0);
    lt1 = fmaf(vt, t_wf[2 * k + 1], lt1);
    lf0 = fmaf(vf, f_wf[2 * k],     lf0);
    lf1 = fmaf(vf, f_wf[2 * k + 1], lf1);
  }
  float m  = fmaxf(lt0, lt1);
  float e0 = expf(lt0 - m), e1 = expf(lt1 - m);
  float conf = fmaxf(e0, e1) / (e0 + e1);
  bool use2 = (conf <= 0.9f);
  out[2 * b]     = use2 ? 0.7f * lt0 + 0.3f * lf0 : lt0;
  out[2 * b + 1] = use2 ? 0.7f * lt1 + 0.3f * lf1 : lt1;
  unsigned long long mask = __ballot(use2);
  if (b == 0) out[128] = (float)__popcll(mask) * (1.0f / 64.0f);
}

extern "C" void kernel_launch(void* const* d_in, const int* in_sizes, int n_in,
                              void* d_out, int out_size, void* d_ws, size_t ws_size,
                              hipStream_t stream) {
  const float* x    = (const float*)d_in[0];
  const float* t_w1 = (const float*)d_in[1];
  const float* t_b1 = (const float*)d_in[2];
  const float* t_w2 = (const float*)d_in[3];
  const float* t_b2 = (const float*)d_in[4];
  const float* t_wf = (const float*)d_in[5];
  const float* t_bf = (const float*)d_in[6];
  const float* f_w1 = (const float*)d_in[7];
  const float* f_b1 = (const float*)d_in[8];
  const float* f_w2 = (const float*)d_in[9];
  const float* f_b2 = (const float*)d_in[10];
  const float* f_wf = (const float*)d_in[11];
  const float* f_bf = (const float*)d_in[12];
  float* out = (float*)d_out;

  float* w2t = (float*)d_ws;            // 2*576*128 floats
  float* g   = w2t + 2 * 576 * 128;     // 2*64*128 floats

  hipMemsetAsync(g, 0, 2 * 64 * 128 * sizeof(float), stream);
  transpose_w2<<<576, 256, 0, stream>>>(t_w2, f_w2, w2t);
  fused_expert<<<dim3(28, 64, 2), 256, 0, stream>>>(
      x, t_w1, t_b1, t_b2, f_w1, f_b1, f_b2, w2t, g);
  finale<<<1, 64, 0, stream>>>(g, t_wf, t_bf, f_wf, f_bf, out);
}